// Round 8
// baseline (3997.419 us; speedup 1.0000x reference)
//
#include <hip/hip_runtime.h>
#include <hip/hip_bf16.h>
#include <cstddef>

#define BATCH 16
#define TSTEPS 128
#define MSLOTS 512
#define DIN 256
#define UNITS 256
#define ZDIM 1024
#define G 8          // blocks per batch
#define NBLK (BATCH*G)
#define NTHR 512

static __device__ __forceinline__ float tanhf_fast(float x) {
    float e = __expf(2.0f * x);
    return 1.0f - 2.0f / (e + 1.0f);
}
static __device__ __forceinline__ float sigmoidf_fast(float x) {
    return 1.0f / (1.0f + __expf(-x));
}
static __device__ __forceinline__ void st_agent_u(unsigned* p, unsigned v) {
    __hip_atomic_store(p, v, __ATOMIC_RELAXED, __HIP_MEMORY_SCOPE_AGENT);
}
static __device__ __forceinline__ unsigned ld_agent_u(const unsigned* p) {
    return __hip_atomic_load(p, __ATOMIC_RELAXED, __HIP_MEMORY_SCOPE_AGENT);
}
// pack two f32 -> bf16 pair (rne); lo = a, hi = b
static __device__ __forceinline__ unsigned pack_bf(float a, float b) {
    unsigned ua = __float_as_uint(a); ua = (ua + 0x7fffu + ((ua >> 16) & 1u)) >> 16;
    unsigned ub = __float_as_uint(b); ub = ((ub + 0x7fffu + ((ub >> 16) & 1u)) >> 16) << 16;
    return ua | ub;
}
static __device__ __forceinline__ float bf_lo(unsigned w) { return __uint_as_float(w << 16); }
static __device__ __forceinline__ float bf_hi(unsigned w) { return __uint_as_float(w & 0xffff0000u); }

// ---------------------------------------------------------------------------
// f32 GEMM + bias: C[M][N] = A @ B + bias. 64x64 tile, 256 thr, 4x4/thread.
// ---------------------------------------------------------------------------
__global__ __launch_bounds__(256) void gemm_bias_kernel(
    const float* __restrict__ A, const float* __restrict__ B,
    const float* __restrict__ bias, float* __restrict__ C,
    int M, int N, int K)
{
    __shared__ float As[16][68];
    __shared__ float Bs[16][68];
    const int tid = threadIdx.x;
    const int bm = blockIdx.x * 64;
    const int bn = blockIdx.y * 64;
    const int tx = tid & 15, ty = tid >> 4;
    const int ar = tid >> 2, ac = (tid & 3) * 4;
    const int br = tid >> 4, bc = (tid & 15) * 4;
    float acc[4][4] = {};

    for (int k0 = 0; k0 < K; k0 += 16) {
        float4 av = *(const float4*)(A + (size_t)(bm + ar) * K + k0 + ac);
        float4 bv = *(const float4*)(B + (size_t)(k0 + br) * N + bn + bc);
        As[ac + 0][ar] = av.x; As[ac + 1][ar] = av.y;
        As[ac + 2][ar] = av.z; As[ac + 3][ar] = av.w;
        *(float4*)(&Bs[br][bc]) = bv;
        __syncthreads();
#pragma unroll
        for (int kk = 0; kk < 16; ++kk) {
            float a0 = As[kk][ty*4+0], a1 = As[kk][ty*4+1];
            float a2 = As[kk][ty*4+2], a3 = As[kk][ty*4+3];
            float b0 = Bs[kk][tx*4+0], b1 = Bs[kk][tx*4+1];
            float b2 = Bs[kk][tx*4+2], b3 = Bs[kk][tx*4+3];
            acc[0][0]+=a0*b0; acc[0][1]+=a0*b1; acc[0][2]+=a0*b2; acc[0][3]+=a0*b3;
            acc[1][0]+=a1*b0; acc[1][1]+=a1*b1; acc[1][2]+=a1*b2; acc[1][3]+=a1*b3;
            acc[2][0]+=a2*b0; acc[2][1]+=a2*b1; acc[2][2]+=a2*b2; acc[2][3]+=a2*b3;
            acc[3][0]+=a3*b0; acc[3][1]+=a3*b1; acc[3][2]+=a3*b2; acc[3][3]+=a3*b3;
        }
        __syncthreads();
    }
#pragma unroll
    for (int i = 0; i < 4; ++i)
#pragma unroll
        for (int j = 0; j < 4; ++j) {
            int cn = bn + tx * 4 + j;
            C[(size_t)(bm + ty * 4 + i) * N + cn] = acc[i][j] + bias[cn];
        }
}

// ---------------------------------------------------------------------------
// GEMM, no bias, bf16 output, per-batch TRANSPOSED store: CT[b][n][m] ushort.
// A rows are batch-major (512 rows per batch). Used for AW2 = attended @ W2.
// ---------------------------------------------------------------------------
__global__ __launch_bounds__(256) void gemm_T_bf16_kernel(
    const float* __restrict__ A, const float* __restrict__ B,
    unsigned short* __restrict__ CT, int M, int N, int K)
{
    __shared__ float As[16][68];
    __shared__ float Bs[16][68];
    __shared__ float Ts[64][65];
    const int tid = threadIdx.x;
    const int bm = blockIdx.x * 64;
    const int bn = blockIdx.y * 64;
    const int tx = tid & 15, ty = tid >> 4;
    const int ar = tid >> 2, ac = (tid & 3) * 4;
    const int br = tid >> 4, bc = (tid & 15) * 4;
    float acc[4][4] = {};

    for (int k0 = 0; k0 < K; k0 += 16) {
        float4 av = *(const float4*)(A + (size_t)(bm + ar) * K + k0 + ac);
        float4 bv = *(const float4*)(B + (size_t)(k0 + br) * N + bn + bc);
        As[ac + 0][ar] = av.x; As[ac + 1][ar] = av.y;
        As[ac + 2][ar] = av.z; As[ac + 3][ar] = av.w;
        *(float4*)(&Bs[br][bc]) = bv;
        __syncthreads();
#pragma unroll
        for (int kk = 0; kk < 16; ++kk) {
            float a0 = As[kk][ty*4+0], a1 = As[kk][ty*4+1];
            float a2 = As[kk][ty*4+2], a3 = As[kk][ty*4+3];
            float b0 = Bs[kk][tx*4+0], b1 = Bs[kk][tx*4+1];
            float b2 = Bs[kk][tx*4+2], b3 = Bs[kk][tx*4+3];
            acc[0][0]+=a0*b0; acc[0][1]+=a0*b1; acc[0][2]+=a0*b2; acc[0][3]+=a0*b3;
            acc[1][0]+=a1*b0; acc[1][1]+=a1*b1; acc[1][2]+=a1*b2; acc[1][3]+=a1*b3;
            acc[2][0]+=a2*b0; acc[2][1]+=a2*b1; acc[2][2]+=a2*b2; acc[2][3]+=a2*b3;
            acc[3][0]+=a3*b0; acc[3][1]+=a3*b1; acc[3][2]+=a3*b2; acc[3][3]+=a3*b3;
        }
        __syncthreads();
    }
#pragma unroll
    for (int i = 0; i < 4; ++i)
#pragma unroll
        for (int j = 0; j < 4; ++j)
            Ts[tx * 4 + j][ty * 4 + i] = acc[i][j];
    __syncthreads();
    const int jr = tid >> 2, ms2 = (tid & 3) * 16;
    const int b = bm >> 9, m0 = bm & 511;
    unsigned short* dst = CT + (size_t)b * ((size_t)N * 512)
                        + (size_t)(bn + jr) * 512 + m0 + ms2;
#pragma unroll
    for (int u = 0; u < 16; ++u) {
        unsigned ua = __float_as_uint(Ts[jr][ms2 + u]);
        ua = (ua + 0x7fffu + ((ua >> 16) & 1u)) >> 16;
        dst[u] = (unsigned short)ua;
    }
}

// ---------------------------------------------------------------------------
// Persistent scan: 128 blocks (8 per batch, XCD-clustered), 512 threads.
// __launch_bounds__(512, 1): VGPR cap 256 so the 176-word weight arrays are
// TRUE registers (at (512,2)/128-VGPR they spilled to scratch -> 3.2GB/launch
// of HBM scratch re-reads, which was the entire R5-R7 bottleneck).
// Sentinel exchange, fence-free: wave 0 stores payload (UC, agent scope) ->
// s_waitcnt vmcnt(0) -> lane 0 stores sentinel(tag=t). Consumers poll only
// the 7 foreign sentinels with 7 lanes, then read payload once (no polling).
// ---------------------------------------------------------------------------
__global__ __launch_bounds__(NTHR, 1) void rnn_persistent(
    const float* __restrict__ query_W, const float* __restrict__ query_b,
    const float* __restrict__ attn_W,  const float* __restrict__ lstm_U,
    const float* __restrict__ keys,    const float* __restrict__ pre,
    const unsigned short* __restrict__ aw2T,
    unsigned* pB, unsigned* hB, unsigned* sent,
    float* __restrict__ seq, float* __restrict__ hT, float* __restrict__ cT)
{
    const int bid = blockIdx.x;
    // XCD clustering heuristic (perf only): a batch's 8 blocks share bid%8
    const int b = (bid & 7) * 2 + (bid >> 6);
    const int g = (bid >> 3) & 7;
    const int tid = threadIdx.x;

    __shared__ __align__(16) float h_s[256];
    __shared__ __align__(16) float q_s[256];
    __shared__ __align__(16) float qp_s[8][256];
    __shared__ __align__(16) float aw_s[256];
    __shared__ __align__(16) float qb_s[256];
    __shared__ __align__(16) float pown_s[64];
    __shared__ __align__(16) float pgat_s[512];
    __shared__ __align__(16) float zp_s[8][128];
    __shared__ __align__(16) float z_s[128];
    __shared__ __align__(16) float red_s[8];

    // roles
    const int c64 = tid & 63, ms = tid >> 6;      // z-phase: 2 cols, m/k-slice ms
    const int j4  = tid & 63, kh = tid >> 6;      // q-phase: 4 cols, k-block kh
    const int mloc = tid >> 3, pp = tid & 7;      // scores: own m, j-octant pp

    const int cc0 = 2 * c64, cc1 = 2 * c64 + 1;
    const int col0 = ((cc0 >> 5) << 8) + g * 32 + (cc0 & 31);
    const int col1 = ((cc1 >> 5) << 8) + g * 32 + (cc1 & 31);

    // ---- t-invariant register state (fits in 256-VGPR budget) ----
    unsigned wq_r[4][16];    // Wq[kh*32+2i(+1)][j4*4+cc] bf16 pairs (pack along k)
#pragma unroll
    for (int cci = 0; cci < 4; ++cci) {
        int j = j4 * 4 + cci;
#pragma unroll
        for (int i = 0; i < 16; ++i)
            wq_r[cci][i] = pack_bf(query_W[(size_t)(kh * 32 + 2 * i) * 256 + j],
                                   query_W[(size_t)(kh * 32 + 2 * i + 1) * 256 + j]);
    }
    unsigned keys_r[16];     // keys[b][g*64+mloc][pp*32 + 2*jp(+1)], pre-rotated
    {
        const float* krow = keys + ((size_t)(b * MSLOTS + g * 64 + mloc)) * 256 + pp * 32;
#pragma unroll
        for (int i = 0; i < 16; ++i) {
            int jp = (i + pp * 2) & 15;
            keys_r[i] = pack_bf(krow[jp * 2], krow[jp * 2 + 1]);
        }
    }
    unsigned u_r[2][16];     // U[ms*32+2j(+1)][col] bf16 pairs (pack along k)
#pragma unroll
    for (int j = 0; j < 16; ++j) {
        u_r[0][j] = pack_bf(lstm_U[(size_t)(ms * 32 + 2 * j) * ZDIM + col0],
                            lstm_U[(size_t)(ms * 32 + 2 * j + 1) * ZDIM + col0]);
        u_r[1][j] = pack_bf(lstm_U[(size_t)(ms * 32 + 2 * j) * ZDIM + col1],
                            lstm_U[(size_t)(ms * 32 + 2 * j + 1) * ZDIM + col1]);
    }
    unsigned aw2_r[2][32];   // AW2[m = ms*64 + 2j(+1)][col] bf16 pairs (along m)
    {
        const unsigned* a0 = (const unsigned*)(aw2T + ((size_t)b * ZDIM + col0) * 512 + ms * 64);
        const unsigned* a1 = (const unsigned*)(aw2T + ((size_t)b * ZDIM + col1) * 512 + ms * 64);
#pragma unroll
        for (int j = 0; j < 32; ++j) { aw2_r[0][j] = a0[j]; aw2_r[1][j] = a1[j]; }
    }

    if (tid < 256) { aw_s[tid] = attn_W[tid]; qb_s[tid] = query_b[tid]; h_s[tid] = 0.0f; }
    float c_r = 0.0f;   // cell state for unit g*32 + tid (tid<32); block-local
    __syncthreads();

    const float* preb = pre + (size_t)b * TSTEPS * ZDIM;
    unsigned* pBb = pB + b * 512;
    unsigned* hBb = hB + b * 256;
    unsigned* sentb = sent + b * 32;   // [0..7]=p sentinels, [16..23]=h sentinels

    for (int t = 0; t < TSTEPS; ++t) {
        const unsigned tag = (unsigned)t;   // 0..127; init 0xFFFFFFFF never matches
        // hoisted pre load for this thread's z-reduce role (tid<128)
        float pre_r = 0.0f;
        if (tid < 128)
            pre_r = preb[(size_t)t * ZDIM + ((tid >> 5) << 8) + g * 32 + (tid & 31)];

        // ---- phase Q: q = h @ Wq + qb (redundant per block, from registers) ----
        {
            float qa0 = 0.f, qa1 = 0.f, qa2 = 0.f, qa3 = 0.f;
#pragma unroll
            for (int i = 0; i < 16; ++i) {
                float2 hv = *(const float2*)&h_s[kh * 32 + 2 * i];
                unsigned w0 = wq_r[0][i], w1 = wq_r[1][i], w2 = wq_r[2][i], w3 = wq_r[3][i];
                qa0 += hv.x * bf_lo(w0) + hv.y * bf_hi(w0);
                qa1 += hv.x * bf_lo(w1) + hv.y * bf_hi(w1);
                qa2 += hv.x * bf_lo(w2) + hv.y * bf_hi(w2);
                qa3 += hv.x * bf_lo(w3) + hv.y * bf_hi(w3);
            }
            *(float4*)&qp_s[kh][j4 * 4] = make_float4(qa0, qa1, qa2, qa3);
        }
        __syncthreads();
        if (tid < 256) {
            float acc = qb_s[tid];
#pragma unroll
            for (int i = 0; i < 8; ++i) acc += qp_s[i][tid];
            q_s[tid] = acc;
        }
        __syncthreads();

        // ---- phase S: scores + exp for own 64 m (keys in registers) ----
        {
            float sacc = 0.0f;
#pragma unroll
            for (int i = 0; i < 16; ++i) {
                int jp = (i + pp * 2) & 15;
                int j = pp * 32 + jp * 2;
                float2 qv = *(const float2*)&q_s[j];
                float2 av = *(const float2*)&aw_s[j];
                unsigned kw = keys_r[i];
                sacc += av.x * tanhf_fast(bf_lo(kw) + qv.x);
                sacc += av.y * tanhf_fast(bf_hi(kw) + qv.y);
            }
            sacc += __shfl_xor(sacc, 1);
            sacc += __shfl_xor(sacc, 2);
            sacc += __shfl_xor(sacc, 4);
            if (pp == 0) pown_s[mloc] = __expf(sacc);   // |s| <= ~13, no max-sub
        }
        __syncthreads();   // pown_s ready

        // ---- publish p: wave 0 stores payload, drains, then sentinel ----
        if (tid < 64) {
            st_agent_u(&pBb[g * 64 + tid], __float_as_uint(pown_s[tid]));
            asm volatile("s_waitcnt vmcnt(0)" ::: "memory");
            if (tid == 0) st_agent_u(&sentb[g], tag);
        }

        // ---- z_h from registers (independent of p) — hides drain + poll ----
        float zh0 = 0.f, zh1 = 0.f;
#pragma unroll
        for (int i = 0; i < 8; ++i) {
            float4 hv = *(const float4*)&h_s[ms * 32 + i * 4];
            unsigned w00 = u_r[0][2*i], w01 = u_r[0][2*i+1];
            unsigned w10 = u_r[1][2*i], w11 = u_r[1][2*i+1];
            zh0 += hv.x*bf_lo(w00) + hv.y*bf_hi(w00) + hv.z*bf_lo(w01) + hv.w*bf_hi(w01);
            zh1 += hv.x*bf_lo(w10) + hv.y*bf_hi(w10) + hv.z*bf_lo(w11) + hv.w*bf_hi(w11);
        }

        // ---- poll 7 foreign p-sentinels (7 lanes only) ----
        if (tid < 8 && tid != g) {
            while (ld_agent_u(&sentb[tid]) != tag)
                __builtin_amdgcn_s_sleep(2);
        }
        __syncthreads();

        // ---- gather p (single read burst; own slice from LDS) ----
        float pv;
        if ((tid >> 6) == g) pv = pown_s[tid & 63];
        else                 pv = __uint_as_float(ld_agent_u(&pBb[tid]));
        pgat_s[tid] = pv;
        // denom reduction (wave, then cross-wave)
        {
            float dv = pv;
            dv += __shfl_xor(dv, 1);  dv += __shfl_xor(dv, 2);  dv += __shfl_xor(dv, 4);
            dv += __shfl_xor(dv, 8);  dv += __shfl_xor(dv, 16); dv += __shfl_xor(dv, 32);
            if ((tid & 63) == 0) red_s[tid >> 6] = dv;
        }
        __syncthreads();
        float inv;
        {
            float tot = red_s[0] + red_s[1] + red_s[2] + red_s[3]
                      + red_s[4] + red_s[5] + red_s[6] + red_s[7];
            inv = 1.0f / tot;
        }

        // ---- phase Z: own 2 cols from registers ----
        {
            float zc0 = 0.f, zc1 = 0.f;
#pragma unroll
            for (int i = 0; i < 16; ++i) {
                float4 pvv = *(const float4*)&pgat_s[ms * 64 + i * 4];
                unsigned w00 = aw2_r[0][2*i], w01 = aw2_r[0][2*i+1];
                unsigned w10 = aw2_r[1][2*i], w11 = aw2_r[1][2*i+1];
                zc0 += pvv.x*bf_lo(w00) + pvv.y*bf_hi(w00) + pvv.z*bf_lo(w01) + pvv.w*bf_hi(w01);
                zc1 += pvv.x*bf_lo(w10) + pvv.y*bf_hi(w10) + pvv.z*bf_lo(w11) + pvv.w*bf_hi(w11);
            }
            *(float2*)&zp_s[ms][c64 * 2] = make_float2(zc0 * inv + zh0, zc1 * inv + zh1);
        }
        __syncthreads();
        if (tid < 128) {
            float z = pre_r;
#pragma unroll
            for (int i = 0; i < 8; ++i) z += zp_s[i][tid];
            z_s[tid] = z;
        }
        __syncthreads();

        // ---- gates + state for own 32 units; publish h + sentinel ----
        if (tid < 32) {
            float zi = z_s[tid], zf = z_s[32 + tid], zg = z_s[64 + tid], zo = z_s[96 + tid];
            float ig = sigmoidf_fast(zi);
            float fg = sigmoidf_fast(zf);
            float gg = tanhf_fast(zg);
            float og = sigmoidf_fast(zo);
            float cn = fg * c_r + ig * gg;
            float hn = og * tanhf_fast(cn);
            c_r = cn;
            int u = g * 32 + tid;
            h_s[u] = hn;
            st_agent_u(&hBb[u], __float_as_uint(hn));
            seq[((size_t)b * TSTEPS + t) * UNITS + u] = hn;
            if (t == TSTEPS - 1) { hT[b * UNITS + u] = hn; cT[b * UNITS + u] = cn; }
        }
        if (tid < 64) {   // wave 0: drain payload stores, then sentinel
            asm volatile("s_waitcnt vmcnt(0)" ::: "memory");
            if (tid == 0) st_agent_u(&sentb[16 + g], tag);
        }

        // ---- poll 7 foreign h-sentinels; gather h once ----
        if (tid < 8 && tid != g) {
            while (ld_agent_u(&sentb[16 + tid]) != tag)
                __builtin_amdgcn_s_sleep(2);
        }
        __syncthreads();
        if (tid < 256 && (tid >> 5) != g)
            h_s[tid] = __uint_as_float(ld_agent_u(&hBb[tid]));
        __syncthreads();
    }
}

// ---------------------------------------------------------------------------
extern "C" void kernel_launch(void* const* d_in, const int* in_sizes, int n_in,
                              void* d_out, int out_size, void* d_ws, size_t ws_size,
                              hipStream_t stream)
{
    (void)in_sizes; (void)n_in; (void)out_size; (void)ws_size;
    const float* inputs   = (const float*)d_in[0];
    const float* attended = (const float*)d_in[1];
    const float* key_W    = (const float*)d_in[2];
    const float* key_b    = (const float*)d_in[3];
    const float* query_W  = (const float*)d_in[4];
    const float* query_b  = (const float*)d_in[5];
    const float* attn_W   = (const float*)d_in[6];
    const float* lstm_W   = (const float*)d_in[8];
    const float* lstm_U   = (const float*)d_in[9];
    const float* lstm_b   = (const float*)d_in[10];
    // attn_b (d_in[7]) cancels in softmax — dropped.

    float* out = (float*)d_out;
    float* seq = out;
    float* hT  = out + (size_t)BATCH * TSTEPS * UNITS;
    float* cT  = hT + BATCH * UNITS;

    float* ws = (float*)d_ws;
    float* keys = ws;                                        // 2,097,152 f
    float* pre  = keys + 2097152;                            // 2,097,152 f
    unsigned short* aw2T = (unsigned short*)(pre + 2097152); // 16*1024*512 ushort
    unsigned* pB = (unsigned*)(aw2T + (size_t)16 * 1024 * 512); // 16*512 u32
    unsigned* hB = pB + BATCH * 512;                            // 16*256 u32
    unsigned* sent = hB + BATCH * 256;                          // 16*32 u32

    // reset sentinels to 0xFFFFFFFF (never a valid tag) — replay-safe
    hipMemsetAsync(sent, 0xFF, (size_t)BATCH * 32 * sizeof(unsigned), stream);

    // keys = attended @ key_W + key_b          (8192 x 256)
    gemm_bias_kernel<<<dim3(128, 4), 256, 0, stream>>>(
        attended, key_W, key_b, keys, 8192, 256, 256);
    // pre = inputs @ lstm_W[:256] + lstm_b     (2048 x 1024)
    gemm_bias_kernel<<<dim3(32, 16), 256, 0, stream>>>(
        inputs, lstm_W, lstm_b, pre, 2048, 1024, 256);
    // AW2^T (bf16) = (attended @ lstm_W[256:])^T per batch: [b][1024][512]
    gemm_T_bf16_kernel<<<dim3(128, 16), 256, 0, stream>>>(
        attended, lstm_W + (size_t)256 * ZDIM, aw2T, 8192, 1024, 256);

    rnn_persistent<<<dim3(NBLK), dim3(NTHR), 0, stream>>>(
        query_W, query_b, attn_W, lstm_U,
        keys, pre, aw2T, pB, hB, sent, seq, hT, cT);
}

// Round 10
// 1778.201 us; speedup vs baseline: 2.2480x; 2.2480x over previous
//
#include <hip/hip_runtime.h>
#include <hip/hip_bf16.h>
#include <cstddef>

#define BATCH 16
#define TSTEPS 128
#define MSLOTS 512
#define DIN 256
#define UNITS 256
#define ZDIM 1024
#define G 8          // blocks per batch
#define NBLK (BATCH*G)
#define NTHR 1024

static __device__ __forceinline__ float tanhf_fast(float x) {
    float e = __expf(2.0f * x);
    return 1.0f - 2.0f / (e + 1.0f);
}
static __device__ __forceinline__ float sigmoidf_fast(float x) {
    return 1.0f / (1.0f + __expf(-x));
}
static __device__ __forceinline__ void st_agent_u(unsigned* p, unsigned v) {
    __hip_atomic_store(p, v, __ATOMIC_RELAXED, __HIP_MEMORY_SCOPE_AGENT);
}
static __device__ __forceinline__ unsigned ld_agent_u(const unsigned* p) {
    return __hip_atomic_load(p, __ATOMIC_RELAXED, __HIP_MEMORY_SCOPE_AGENT);
}
// pack two f32 -> bf16 pair (rne); lo = a, hi = b
static __device__ __forceinline__ unsigned pack_bf(float a, float b) {
    unsigned ua = __float_as_uint(a); ua = (ua + 0x7fffu + ((ua >> 16) & 1u)) >> 16;
    unsigned ub = __float_as_uint(b); ub = ((ub + 0x7fffu + ((ub >> 16) & 1u)) >> 16) << 16;
    return ua | ub;
}
static __device__ __forceinline__ float bf_lo(unsigned w) { return __uint_as_float(w << 16); }
static __device__ __forceinline__ float bf_hi(unsigned w) { return __uint_as_float(w & 0xffff0000u); }

// ---------------------------------------------------------------------------
// f32 GEMM + bias: C[M][N] = A @ B + bias. 64x64 tile, 256 thr, 4x4/thread.
// ---------------------------------------------------------------------------
__global__ __launch_bounds__(256) void gemm_bias_kernel(
    const float* __restrict__ A, const float* __restrict__ B,
    const float* __restrict__ bias, float* __restrict__ C,
    int M, int N, int K)
{
    __shared__ float As[16][68];
    __shared__ float Bs[16][68];
    const int tid = threadIdx.x;
    const int bm = blockIdx.x * 64;
    const int bn = blockIdx.y * 64;
    const int tx = tid & 15, ty = tid >> 4;
    const int ar = tid >> 2, ac = (tid & 3) * 4;
    const int br = tid >> 4, bc = (tid & 15) * 4;
    float acc[4][4] = {};

    for (int k0 = 0; k0 < K; k0 += 16) {
        float4 av = *(const float4*)(A + (size_t)(bm + ar) * K + k0 + ac);
        float4 bv = *(const float4*)(B + (size_t)(k0 + br) * N + bn + bc);
        As[ac + 0][ar] = av.x; As[ac + 1][ar] = av.y;
        As[ac + 2][ar] = av.z; As[ac + 3][ar] = av.w;
        *(float4*)(&Bs[br][bc]) = bv;
        __syncthreads();
#pragma unroll
        for (int kk = 0; kk < 16; ++kk) {
            float a0 = As[kk][ty*4+0], a1 = As[kk][ty*4+1];
            float a2 = As[kk][ty*4+2], a3 = As[kk][ty*4+3];
            float b0 = Bs[kk][tx*4+0], b1 = Bs[kk][tx*4+1];
            float b2 = Bs[kk][tx*4+2], b3 = Bs[kk][tx*4+3];
            acc[0][0]+=a0*b0; acc[0][1]+=a0*b1; acc[0][2]+=a0*b2; acc[0][3]+=a0*b3;
            acc[1][0]+=a1*b0; acc[1][1]+=a1*b1; acc[1][2]+=a1*b2; acc[1][3]+=a1*b3;
            acc[2][0]+=a2*b0; acc[2][1]+=a2*b1; acc[2][2]+=a2*b2; acc[2][3]+=a2*b3;
            acc[3][0]+=a3*b0; acc[3][1]+=a3*b1; acc[3][2]+=a3*b2; acc[3][3]+=a3*b3;
        }
        __syncthreads();
    }
#pragma unroll
    for (int i = 0; i < 4; ++i)
#pragma unroll
        for (int j = 0; j < 4; ++j) {
            int cn = bn + tx * 4 + j;
            C[(size_t)(bm + ty * 4 + i) * N + cn] = acc[i][j] + bias[cn];
        }
}

// ---------------------------------------------------------------------------
// GEMM, no bias, bf16 output, per-batch TRANSPOSED store: CT[b][n][m] ushort.
// A rows are batch-major (512 rows per batch). Used for AW2 = attended @ W2.
// ---------------------------------------------------------------------------
__global__ __launch_bounds__(256) void gemm_T_bf16_kernel(
    const float* __restrict__ A, const float* __restrict__ B,
    unsigned short* __restrict__ CT, int M, int N, int K)
{
    __shared__ float As[16][68];
    __shared__ float Bs[16][68];
    __shared__ float Ts[64][65];
    const int tid = threadIdx.x;
    const int bm = blockIdx.x * 64;
    const int bn = blockIdx.y * 64;
    const int tx = tid & 15, ty = tid >> 4;
    const int ar = tid >> 2, ac = (tid & 3) * 4;
    const int br = tid >> 4, bc = (tid & 15) * 4;
    float acc[4][4] = {};

    for (int k0 = 0; k0 < K; k0 += 16) {
        float4 av = *(const float4*)(A + (size_t)(bm + ar) * K + k0 + ac);
        float4 bv = *(const float4*)(B + (size_t)(k0 + br) * N + bn + bc);
        As[ac + 0][ar] = av.x; As[ac + 1][ar] = av.y;
        As[ac + 2][ar] = av.z; As[ac + 3][ar] = av.w;
        *(float4*)(&Bs[br][bc]) = bv;
        __syncthreads();
#pragma unroll
        for (int kk = 0; kk < 16; ++kk) {
            float a0 = As[kk][ty*4+0], a1 = As[kk][ty*4+1];
            float a2 = As[kk][ty*4+2], a3 = As[kk][ty*4+3];
            float b0 = Bs[kk][tx*4+0], b1 = Bs[kk][tx*4+1];
            float b2 = Bs[kk][tx*4+2], b3 = Bs[kk][tx*4+3];
            acc[0][0]+=a0*b0; acc[0][1]+=a0*b1; acc[0][2]+=a0*b2; acc[0][3]+=a0*b3;
            acc[1][0]+=a1*b0; acc[1][1]+=a1*b1; acc[1][2]+=a1*b2; acc[1][3]+=a1*b3;
            acc[2][0]+=a2*b0; acc[2][1]+=a2*b1; acc[2][2]+=a2*b2; acc[2][3]+=a2*b3;
            acc[3][0]+=a3*b0; acc[3][1]+=a3*b1; acc[3][2]+=a3*b2; acc[3][3]+=a3*b3;
        }
        __syncthreads();
    }
#pragma unroll
    for (int i = 0; i < 4; ++i)
#pragma unroll
        for (int j = 0; j < 4; ++j)
            Ts[tx * 4 + j][ty * 4 + i] = acc[i][j];
    __syncthreads();
    const int jr = tid >> 2, ms2 = (tid & 3) * 16;
    const int b = bm >> 9, m0 = bm & 511;
    unsigned short* dst = CT + (size_t)b * ((size_t)N * 512)
                        + (size_t)(bn + jr) * 512 + m0 + ms2;
#pragma unroll
    for (int u = 0; u < 16; ++u) {
        unsigned ua = __float_as_uint(Ts[jr][ms2 + u]);
        ua = (ua + 0x7fffu + ((ua >> 16) & 1u)) >> 16;
        dst[u] = (unsigned short)ua;
    }
}

// ---------------------------------------------------------------------------
// Persistent scan: 128 blocks (8 per batch), 1024 threads, ONE exchange/step.
// Block (b,g): m-slice 64 slots, col-slice 128 z-cols. Publishes zc partials
// for ALL cols (AW2 m-slice in regs), zhp = pre + h@U for own cols, d_g.
// All blocks gather, rebuild full z redundantly -> gates -> full h,c local.
// No h exchange. Only proven UC primitives; syncthreads-drain before sentinel.
// Regs: keys 8 + U 16 + AW2 32 = 56 u32 (<128 cap at 4 waves/EU -> no spill).
// Wq lives in LDS (128 KB bf16).
// ---------------------------------------------------------------------------
__global__ __launch_bounds__(NTHR, 4) void rnn_persistent(
    const float* __restrict__ query_W, const float* __restrict__ query_b,
    const float* __restrict__ attn_W,  const float* __restrict__ lstm_U,
    const float* __restrict__ keys,    const float* __restrict__ pre,
    const unsigned short* __restrict__ aw2T,
    unsigned* zcT, unsigned* zhp, unsigned* dP, unsigned* sent,
    float* __restrict__ seq, float* __restrict__ hT, float* __restrict__ cT)
{
    const int bid = blockIdx.x;
    const int b = bid >> 3, g = bid & 7;
    const int tid = threadIdx.x;

    __shared__ unsigned Wq2[128 * 256];            // 128 KB: Wq bf16 pairs along k
    __shared__ __align__(16) float h_s[256];
    __shared__ __align__(16) float c_s[256];
    __shared__ __align__(16) float q_s[256];
    __shared__ __align__(16) float qp_s[4][256];
    __shared__ __align__(16) float p_s[64];
    __shared__ __align__(16) float zp_s[8][128];
    __shared__ __align__(16) float z_s[1024];
    __shared__ __align__(16) float aw_s[256];
    __shared__ __align__(16) float qb_s[256];
    __shared__ float invd_s;

    // roles
    const int jq = tid & 255, kq = tid >> 8;       // q: col jq, k-quarter kq
    const int mloc = tid >> 4, jc = tid & 15;      // scores: own m, j-comb jc
    const int cc = tid & 127, ks = tid >> 7;       // zh: own col cc, k-slice ks
    const int col_own = ((cc >> 5) << 8) + g * 32 + (cc & 31);

    // ---- prologue: Wq -> LDS (bf16 pairs packed along k) ----
    for (int i = tid; i < 128 * 256; i += NTHR) {
        int k2 = i >> 8, j = i & 255;
        Wq2[i] = pack_bf(query_W[(size_t)(2 * k2) * 256 + j],
                         query_W[(size_t)(2 * k2 + 1) * 256 + j]);
    }
    // keys own m-row, interleaved j (j = jc+32i and jc+32i+16), bf16 pairs
    unsigned keys_r[8];
    {
        const float* krow = keys + (size_t)(b * MSLOTS + g * 64 + mloc) * 256;
#pragma unroll
        for (int i = 0; i < 8; ++i)
            keys_r[i] = pack_bf(krow[jc + 32 * i], krow[jc + 32 * i + 16]);
    }
    // U k-slice for own col (pairs along k)
    unsigned u_r[16];
#pragma unroll
    for (int i = 0; i < 16; ++i)
        u_r[i] = pack_bf(lstm_U[(size_t)(ks * 32 + 2 * i) * ZDIM + col_own],
                         lstm_U[(size_t)(ks * 32 + 2 * i + 1) * ZDIM + col_own]);
    // AW2 own 64-m slice for col = tid (pairs along m)
    unsigned aw2_r[32];
    {
        const unsigned* a0 = (const unsigned*)(aw2T + ((size_t)b * ZDIM + tid) * 512 + g * 64);
#pragma unroll
        for (int i = 0; i < 32; ++i) aw2_r[i] = a0[i];
    }

    if (tid < 256) {
        aw_s[tid] = attn_W[tid];
        qb_s[tid] = query_b[tid];
        h_s[tid] = 0.0f;
        c_s[tid] = 0.0f;
    }
    __syncthreads();

    const float* preb = pre + (size_t)b * TSTEPS * ZDIM;
    unsigned* sentb = sent + b * 16;

    for (int t = 0; t < TSTEPS; ++t) {
        const int par = t & 1;
        const unsigned tag = (unsigned)(t + 1);
        unsigned* zcb = zcT + (size_t)(par * BATCH + b) * 1024 * 8;
        unsigned* zhb = zhp + (size_t)(par * BATCH + b) * 1024;
        unsigned* dPb = dP + (size_t)(par * BATCH + b) * 8;

        float pre_r = 0.0f;
        if (tid < 128)
            pre_r = preb[(size_t)t * ZDIM + col_own];

        // ---- zh partial (own col, k-slice) ----
        {
            float zh = 0.0f;
#pragma unroll
            for (int i = 0; i < 16; ++i) {
                float2 hv = *(const float2*)&h_s[ks * 32 + 2 * i];
                zh += hv.x * bf_lo(u_r[i]) + hv.y * bf_hi(u_r[i]);
            }
            zp_s[ks][cc] = zh;
        }
        // ---- q partial (redundant per block, Wq from LDS) ----
        {
            float qa = 0.0f;
#pragma unroll
            for (int i = 0; i < 32; ++i) {
                unsigned w = Wq2[(kq * 32 + i) * 256 + jq];
                float2 hv = *(const float2*)&h_s[kq * 64 + 2 * i];
                qa += hv.x * bf_lo(w) + hv.y * bf_hi(w);
            }
            qp_s[kq][jq] = qa;
        }
        __syncthreads();
        if (tid < 256)
            q_s[tid] = qb_s[tid] + qp_s[0][tid] + qp_s[1][tid] + qp_s[2][tid] + qp_s[3][tid];
        // zhp publish early (only needs zp/pre) — latency hides under scores
        if (tid < 128) {
            float zv = pre_r + zp_s[0][tid] + zp_s[1][tid] + zp_s[2][tid] + zp_s[3][tid]
                     + zp_s[4][tid] + zp_s[5][tid] + zp_s[6][tid] + zp_s[7][tid];
            st_agent_u(&zhb[col_own], __float_as_uint(zv));
        }
        __syncthreads();

        // ---- scores + exp for own 64 m (interleaved j: conflict-free LDS) ----
        {
            float sacc = 0.0f;
#pragma unroll
            for (int i = 0; i < 8; ++i) {
                int j0 = jc + 32 * i, j1 = j0 + 16;
                unsigned kw = keys_r[i];
                sacc += aw_s[j0] * tanhf_fast(bf_lo(kw) + q_s[j0]);
                sacc += aw_s[j1] * tanhf_fast(bf_hi(kw) + q_s[j1]);
            }
            sacc += __shfl_xor(sacc, 1);
            sacc += __shfl_xor(sacc, 2);
            sacc += __shfl_xor(sacc, 4);
            sacc += __shfl_xor(sacc, 8);
            if (jc == 0) p_s[mloc] = __expf(sacc);   // |s| <= ~13, no max-sub
        }
        __syncthreads();

        // ---- zc publish: own m-slice contribution to col = tid ----
        {
            float zcv = 0.0f;
#pragma unroll
            for (int i = 0; i < 32; ++i) {
                float2 pv = *(const float2*)&p_s[2 * i];
                zcv += pv.x * bf_lo(aw2_r[i]) + pv.y * bf_hi(aw2_r[i]);
            }
            st_agent_u(&zcb[(size_t)tid * 8 + g], __float_as_uint(zcv));
        }
        // ---- d partial publish ----
        if (tid < 64) {
            float dv = p_s[tid];
            dv += __shfl_xor(dv, 1);  dv += __shfl_xor(dv, 2);  dv += __shfl_xor(dv, 4);
            dv += __shfl_xor(dv, 8);  dv += __shfl_xor(dv, 16); dv += __shfl_xor(dv, 32);
            if (tid == 0) st_agent_u(&dPb[g], __float_as_uint(dv));
        }

        // ---- the ONE barrier: syncthreads drains all waves' stores ----
        __syncthreads();
        if (tid == 0) st_agent_u(&sentb[g], tag);
        if (tid < 8 && tid != g) {
            while (ld_agent_u(&sentb[tid]) < tag)
                __builtin_amdgcn_s_sleep(1);
        }
        __syncthreads();

        // ---- gather: 8 zc partials (32B contiguous) + zhp + d ----
        float zcsum;
        float zhv;
        {
            const unsigned* zrow = &zcb[(size_t)tid * 8];
            float s0 = __uint_as_float(ld_agent_u(&zrow[0]));
            float s1 = __uint_as_float(ld_agent_u(&zrow[1]));
            float s2 = __uint_as_float(ld_agent_u(&zrow[2]));
            float s3 = __uint_as_float(ld_agent_u(&zrow[3]));
            float s4 = __uint_as_float(ld_agent_u(&zrow[4]));
            float s5 = __uint_as_float(ld_agent_u(&zrow[5]));
            float s6 = __uint_as_float(ld_agent_u(&zrow[6]));
            float s7 = __uint_as_float(ld_agent_u(&zrow[7]));
            zcsum = ((s0 + s1) + (s2 + s3)) + ((s4 + s5) + (s6 + s7));
            zhv = __uint_as_float(ld_agent_u(&zhb[tid]));
        }
        if (tid < 8) {
            float dv = __uint_as_float(ld_agent_u(&dPb[tid]));
            dv += __shfl_xor(dv, 1); dv += __shfl_xor(dv, 2); dv += __shfl_xor(dv, 4);
            if (tid == 0) invd_s = 1.0f / dv;
        }
        __syncthreads();
        z_s[tid] = zhv + zcsum * invd_s;
        __syncthreads();

        // ---- gates + full h,c redundantly; write own output slice ----
        if (tid < 256) {
            float zi = z_s[tid], zf = z_s[256 + tid], zg = z_s[512 + tid], zo = z_s[768 + tid];
            float ig = sigmoidf_fast(zi);
            float fg = sigmoidf_fast(zf);
            float gg = tanhf_fast(zg);
            float og = sigmoidf_fast(zo);
            float cn = fg * c_s[tid] + ig * gg;
            float hn = og * tanhf_fast(cn);
            c_s[tid] = cn;
            h_s[tid] = hn;
            if ((tid >> 5) == g) {
                seq[((size_t)b * TSTEPS + t) * UNITS + tid] = hn;
                if (t == TSTEPS - 1) { hT[b * UNITS + tid] = hn; cT[b * UNITS + tid] = cn; }
            }
        }
        __syncthreads();
    }
}

// ---------------------------------------------------------------------------
extern "C" void kernel_launch(void* const* d_in, const int* in_sizes, int n_in,
                              void* d_out, int out_size, void* d_ws, size_t ws_size,
                              hipStream_t stream)
{
    (void)in_sizes; (void)n_in; (void)out_size; (void)ws_size;
    const float* inputs   = (const float*)d_in[0];
    const float* attended = (const float*)d_in[1];
    const float* key_W    = (const float*)d_in[2];
    const float* key_b    = (const float*)d_in[3];
    const float* query_W  = (const float*)d_in[4];
    const float* query_b  = (const float*)d_in[5];
    const float* attn_W   = (const float*)d_in[6];
    const float* lstm_W   = (const float*)d_in[8];
    const float* lstm_U   = (const float*)d_in[9];
    const float* lstm_b   = (const float*)d_in[10];
    // attn_b (d_in[7]) cancels in softmax — dropped.

    float* out = (float*)d_out;
    float* seq = out;
    float* hT  = out + (size_t)BATCH * TSTEPS * UNITS;
    float* cT  = hT + BATCH * UNITS;

    float* ws = (float*)d_ws;
    float* keys = ws;                                        // 2,097,152 f
    float* pre  = keys + 2097152;                            // 2,097,152 f
    unsigned short* aw2T = (unsigned short*)(pre + 2097152); // 16*1024*512 ushort
    unsigned* zcT  = (unsigned*)(aw2T + (size_t)16 * 1024 * 512); // 2*16*1024*8 u32
    unsigned* zhp  = zcT + 2 * BATCH * 1024 * 8;                  // 2*16*1024 u32
    unsigned* dP   = zhp + 2 * BATCH * 1024;                      // 2*16*8 u32
    unsigned* sent = dP + 2 * BATCH * 8;                          // 16*16 u32

    // sentinels zeroed each launch (tags are 1..128) — replay-safe
    hipMemsetAsync(sent, 0, (size_t)BATCH * 16 * sizeof(unsigned), stream);

    // keys = attended @ key_W + key_b          (8192 x 256)
    gemm_bias_kernel<<<dim3(128, 4), 256, 0, stream>>>(
        attended, key_W, key_b, keys, 8192, 256, 256);
    // pre = inputs @ lstm_W[:256] + lstm_b     (2048 x 1024)
    gemm_bias_kernel<<<dim3(32, 16), 256, 0, stream>>>(
        inputs, lstm_W, lstm_b, pre, 2048, 1024, 256);
    // AW2^T (bf16) = (attended @ lstm_W[256:])^T per batch: [b][1024][512]
    gemm_T_bf16_kernel<<<dim3(128, 16), 256, 0, stream>>>(
        attended, lstm_W + (size_t)256 * ZDIM, aw2T, 8192, 1024, 256);

    rnn_persistent<<<dim3(NBLK), dim3(NTHR), 0, stream>>>(
        query_W, query_b, attn_W, lstm_U,
        keys, pre, aw2T, zcT, zhp, dP, sent, seq, hT, cT);
}

// Round 11
// 1606.651 us; speedup vs baseline: 2.4880x; 1.1068x over previous
//
#include <hip/hip_runtime.h>
#include <hip/hip_bf16.h>
#include <cstddef>

#define BATCH 16
#define TSTEPS 128
#define MSLOTS 512
#define DIN 256
#define UNITS 256
#define ZDIM 1024
#define G 8          // blocks per batch
#define NBLK (BATCH*G)
#define NTHR 1024

static __device__ __forceinline__ float tanhf_fast(float x) {
    float e = __expf(2.0f * x);
    return 1.0f - 2.0f / (e + 1.0f);
}
static __device__ __forceinline__ float sigmoidf_fast(float x) {
    return 1.0f / (1.0f + __expf(-x));
}
static __device__ __forceinline__ void st_agent_u(unsigned* p, unsigned v) {
    __hip_atomic_store(p, v, __ATOMIC_RELAXED, __HIP_MEMORY_SCOPE_AGENT);
}
static __device__ __forceinline__ unsigned ld_agent_u(const unsigned* p) {
    return __hip_atomic_load(p, __ATOMIC_RELAXED, __HIP_MEMORY_SCOPE_AGENT);
}
// pack two f32 -> bf16 pair (rne); lo = a, hi = b
static __device__ __forceinline__ unsigned pack_bf(float a, float b) {
    unsigned ua = __float_as_uint(a); ua = (ua + 0x7fffu + ((ua >> 16) & 1u)) >> 16;
    unsigned ub = __float_as_uint(b); ub = ((ub + 0x7fffu + ((ub >> 16) & 1u)) >> 16) << 16;
    return ua | ub;
}
static __device__ __forceinline__ float bf_lo(unsigned w) { return __uint_as_float(w << 16); }
static __device__ __forceinline__ float bf_hi(unsigned w) { return __uint_as_float(w & 0xffff0000u); }

// ---------------------------------------------------------------------------
// f32 GEMM + bias: C[M][N] = A @ B + bias. 64x64 tile, 256 thr, 4x4/thread.
// ---------------------------------------------------------------------------
__global__ __launch_bounds__(256) void gemm_bias_kernel(
    const float* __restrict__ A, const float* __restrict__ B,
    const float* __restrict__ bias, float* __restrict__ C,
    int M, int N, int K)
{
    __shared__ float As[16][68];
    __shared__ float Bs[16][68];
    const int tid = threadIdx.x;
    const int bm = blockIdx.x * 64;
    const int bn = blockIdx.y * 64;
    const int tx = tid & 15, ty = tid >> 4;
    const int ar = tid >> 2, ac = (tid & 3) * 4;
    const int br = tid >> 4, bc = (tid & 15) * 4;
    float acc[4][4] = {};

    for (int k0 = 0; k0 < K; k0 += 16) {
        float4 av = *(const float4*)(A + (size_t)(bm + ar) * K + k0 + ac);
        float4 bv = *(const float4*)(B + (size_t)(k0 + br) * N + bn + bc);
        As[ac + 0][ar] = av.x; As[ac + 1][ar] = av.y;
        As[ac + 2][ar] = av.z; As[ac + 3][ar] = av.w;
        *(float4*)(&Bs[br][bc]) = bv;
        __syncthreads();
#pragma unroll
        for (int kk = 0; kk < 16; ++kk) {
            float a0 = As[kk][ty*4+0], a1 = As[kk][ty*4+1];
            float a2 = As[kk][ty*4+2], a3 = As[kk][ty*4+3];
            float b0 = Bs[kk][tx*4+0], b1 = Bs[kk][tx*4+1];
            float b2 = Bs[kk][tx*4+2], b3 = Bs[kk][tx*4+3];
            acc[0][0]+=a0*b0; acc[0][1]+=a0*b1; acc[0][2]+=a0*b2; acc[0][3]+=a0*b3;
            acc[1][0]+=a1*b0; acc[1][1]+=a1*b1; acc[1][2]+=a1*b2; acc[1][3]+=a1*b3;
            acc[2][0]+=a2*b0; acc[2][1]+=a2*b1; acc[2][2]+=a2*b2; acc[2][3]+=a2*b3;
            acc[3][0]+=a3*b0; acc[3][1]+=a3*b1; acc[3][2]+=a3*b2; acc[3][3]+=a3*b3;
        }
        __syncthreads();
    }
#pragma unroll
    for (int i = 0; i < 4; ++i)
#pragma unroll
        for (int j = 0; j < 4; ++j) {
            int cn = bn + tx * 4 + j;
            C[(size_t)(bm + ty * 4 + i) * N + cn] = acc[i][j] + bias[cn];
        }
}

// ---------------------------------------------------------------------------
// GEMM, no bias, bf16 output, per-batch TRANSPOSED store: CT[b][n][m] ushort.
// A rows are batch-major (512 rows per batch). Used for AW2 = attended @ W2.
// ---------------------------------------------------------------------------
__global__ __launch_bounds__(256) void gemm_T_bf16_kernel(
    const float* __restrict__ A, const float* __restrict__ B,
    unsigned short* __restrict__ CT, int M, int N, int K)
{
    __shared__ float As[16][68];
    __shared__ float Bs[16][68];
    __shared__ float Ts[64][65];
    const int tid = threadIdx.x;
    const int bm = blockIdx.x * 64;
    const int bn = blockIdx.y * 64;
    const int tx = tid & 15, ty = tid >> 4;
    const int ar = tid >> 2, ac = (tid & 3) * 4;
    const int br = tid >> 4, bc = (tid & 15) * 4;
    float acc[4][4] = {};

    for (int k0 = 0; k0 < K; k0 += 16) {
        float4 av = *(const float4*)(A + (size_t)(bm + ar) * K + k0 + ac);
        float4 bv = *(const float4*)(B + (size_t)(k0 + br) * N + bn + bc);
        As[ac + 0][ar] = av.x; As[ac + 1][ar] = av.y;
        As[ac + 2][ar] = av.z; As[ac + 3][ar] = av.w;
        *(float4*)(&Bs[br][bc]) = bv;
        __syncthreads();
#pragma unroll
        for (int kk = 0; kk < 16; ++kk) {
            float a0 = As[kk][ty*4+0], a1 = As[kk][ty*4+1];
            float a2 = As[kk][ty*4+2], a3 = As[kk][ty*4+3];
            float b0 = Bs[kk][tx*4+0], b1 = Bs[kk][tx*4+1];
            float b2 = Bs[kk][tx*4+2], b3 = Bs[kk][tx*4+3];
            acc[0][0]+=a0*b0; acc[0][1]+=a0*b1; acc[0][2]+=a0*b2; acc[0][3]+=a0*b3;
            acc[1][0]+=a1*b0; acc[1][1]+=a1*b1; acc[1][2]+=a1*b2; acc[1][3]+=a1*b3;
            acc[2][0]+=a2*b0; acc[2][1]+=a2*b1; acc[2][2]+=a2*b2; acc[2][3]+=a2*b3;
            acc[3][0]+=a3*b0; acc[3][1]+=a3*b1; acc[3][2]+=a3*b2; acc[3][3]+=a3*b3;
        }
        __syncthreads();
    }
#pragma unroll
    for (int i = 0; i < 4; ++i)
#pragma unroll
        for (int j = 0; j < 4; ++j)
            Ts[tx * 4 + j][ty * 4 + i] = acc[i][j];
    __syncthreads();
    const int jr = tid >> 2, ms2 = (tid & 3) * 16;
    const int b = bm >> 9, m0 = bm & 511;
    unsigned short* dst = CT + (size_t)b * ((size_t)N * 512)
                        + (size_t)(bn + jr) * 512 + m0 + ms2;
#pragma unroll
    for (int u = 0; u < 16; ++u) {
        unsigned ua = __float_as_uint(Ts[jr][ms2 + u]);
        ua = (ua + 0x7fffu + ((ua >> 16) & 1u)) >> 16;
        dst[u] = (unsigned short)ua;
    }
}

// ---------------------------------------------------------------------------
// Persistent scan: 128 blocks (8 per batch), 1024 threads, 2 THIN exchanges.
// Block (b,g): m-slice 64 slots (scores), col-slice 128 z-cols (z + gates
// for own 32 units). Exchange 1: p (64 f32/block). Exchange 2: h (32 f32).
// zc is computed ONCE per col from gathered p via an AW2 col-slice in LDS
// (128 KB) -- no fat zc exchange (R10's 900MB/launch UC traffic).
// Regs: wq 32 + keys 8 + u 16 = 56 u32 -> no spills (R10 compiled VGPR=64).
// Proven UC sentinel protocol: payload -> vmcnt(0) -> sentinel; 7-lane poll.
// ---------------------------------------------------------------------------
__global__ __launch_bounds__(NTHR, 4) void rnn_persistent(
    const float* __restrict__ query_W, const float* __restrict__ query_b,
    const float* __restrict__ attn_W,  const float* __restrict__ lstm_U,
    const float* __restrict__ keys,    const float* __restrict__ pre,
    const unsigned short* __restrict__ aw2T,
    unsigned* pB, unsigned* hB, unsigned* sent,
    float* __restrict__ seq, float* __restrict__ hT, float* __restrict__ cT)
{
    const int bid = blockIdx.x;
    const int b = bid >> 3, g = bid & 7;
    const int tid = threadIdx.x;

    __shared__ unsigned aw2L[256 * 128];   // 128 KB: AW2[m-pair][own col] bf16 pairs
    __shared__ __align__(16) float h_s[256];
    __shared__ __align__(16) float q_s[256];
    __shared__ __align__(16) float qp_s[4][256];
    __shared__ __align__(16) float p_s[512];
    __shared__ __align__(16) float pown_s[64];
    __shared__ __align__(16) float zp_s[8][128];
    __shared__ __align__(16) float z_s[128];
    __shared__ __align__(16) float aw_s[256];
    __shared__ __align__(16) float qb_s[256];
    __shared__ __align__(16) float red_s[8];

    // roles
    const int jq = tid & 255, kq = tid >> 8;     // q: col jq, k-quarter kq
    const int mloc = tid >> 4, jc = tid & 15;    // scores: own m, j-comb jc
    const int cc = tid & 127, ks = tid >> 7;     // z: own col cc, m/k-slice ks
    const int col_own = ((cc >> 5) << 8) + g * 32 + (cc & 31);

    // ---- prologue: AW2 own-col slice -> LDS (pairs along m) ----
    for (int i = tid; i < 256 * 128; i += NTHR) {
        int pr = i >> 7, c2 = i & 127;
        int colc = ((c2 >> 5) << 8) + g * 32 + (c2 & 31);
        aw2L[i] = ((const unsigned*)(aw2T + ((size_t)b * ZDIM + colc) * 512))[pr];
    }
    // Wq in registers: Wq[kq*64 + 2i(+1)][jq] pairs along k
    unsigned wq_r[32];
#pragma unroll
    for (int i = 0; i < 32; ++i)
        wq_r[i] = pack_bf(query_W[(size_t)(kq * 64 + 2 * i) * 256 + jq],
                          query_W[(size_t)(kq * 64 + 2 * i + 1) * 256 + jq]);
    // keys own m-row, interleaved j (j = jc+32i and jc+32i+16), bf16 pairs
    unsigned keys_r[8];
    {
        const float* krow = keys + (size_t)(b * MSLOTS + g * 64 + mloc) * 256;
#pragma unroll
        for (int i = 0; i < 8; ++i)
            keys_r[i] = pack_bf(krow[jc + 32 * i], krow[jc + 32 * i + 16]);
    }
    // U k-slice for own col (pairs along k)
    unsigned u_r[16];
#pragma unroll
    for (int i = 0; i < 16; ++i)
        u_r[i] = pack_bf(lstm_U[(size_t)(ks * 32 + 2 * i) * ZDIM + col_own],
                         lstm_U[(size_t)(ks * 32 + 2 * i + 1) * ZDIM + col_own]);

    if (tid < 256) {
        aw_s[tid] = attn_W[tid];
        qb_s[tid] = query_b[tid];
        h_s[tid] = 0.0f;
    }
    float c_r = 0.0f;   // cell state for unit g*32 + tid (tid<32)
    __syncthreads();

    const float* preb = pre + (size_t)b * TSTEPS * ZDIM;
    unsigned* pBb = pB + b * 512;
    unsigned* hBb = hB + b * 256;
    unsigned* sentb = sent + b * 16;

    for (int t = 0; t < TSTEPS; ++t) {
        const unsigned ptag = (unsigned)(2 * t + 1);
        const unsigned htag = (unsigned)(2 * t + 2);

        float pre_r = 0.0f;
        if (tid < 128)
            pre_r = preb[(size_t)t * ZDIM + col_own];

        // ---- phase 1: q partials (regs) + zh partials (regs), both from h ----
        {
            float qa = 0.0f;
#pragma unroll
            for (int i = 0; i < 32; ++i) {
                float2 hv = *(const float2*)&h_s[kq * 64 + 2 * i];
                qa += hv.x * bf_lo(wq_r[i]) + hv.y * bf_hi(wq_r[i]);
            }
            qp_s[kq][jq] = qa;
        }
        {
            float zh = 0.0f;
#pragma unroll
            for (int i = 0; i < 16; ++i) {
                float2 hv = *(const float2*)&h_s[ks * 32 + 2 * i];
                zh += hv.x * bf_lo(u_r[i]) + hv.y * bf_hi(u_r[i]);
            }
            zp_s[ks][cc] = zh;
        }
        __syncthreads();

        // ---- phase 2: q reduce; zh+pre reduce kept in register (tid<128) ----
        if (tid < 256)
            q_s[tid] = qb_s[tid] + qp_s[0][tid] + qp_s[1][tid] + qp_s[2][tid] + qp_s[3][tid];
        float zv = 0.0f;
        if (tid < 128)
            zv = pre_r + zp_s[0][cc] + zp_s[1][cc] + zp_s[2][cc] + zp_s[3][cc]
               + zp_s[4][cc] + zp_s[5][cc] + zp_s[6][cc] + zp_s[7][cc];
        __syncthreads();

        // ---- phase 3: scores + exp for own 64 m ----
        {
            float sacc = 0.0f;
#pragma unroll
            for (int i = 0; i < 8; ++i) {
                int j0 = jc + 32 * i, j1 = j0 + 16;
                unsigned kw = keys_r[i];
                sacc += aw_s[j0] * tanhf_fast(bf_lo(kw) + q_s[j0]);
                sacc += aw_s[j1] * tanhf_fast(bf_hi(kw) + q_s[j1]);
            }
            sacc += __shfl_xor(sacc, 1);
            sacc += __shfl_xor(sacc, 2);
            sacc += __shfl_xor(sacc, 4);
            sacc += __shfl_xor(sacc, 8);
            if (jc == 0) pown_s[mloc] = __expf(sacc);   // |s| <= ~13, no max-sub
        }
        __syncthreads();

        // ---- exchange 1: publish p (wave 0), poll, gather ----
        if (tid < 64) {
            st_agent_u(&pBb[g * 64 + tid], __float_as_uint(pown_s[tid]));
            asm volatile("s_waitcnt vmcnt(0)" ::: "memory");
            if (tid == 0) st_agent_u(&sentb[g], ptag);
        }
        if (tid < 8 && tid != g) {
            while (ld_agent_u(&sentb[tid]) < ptag)
                __builtin_amdgcn_s_sleep(1);
        }
        __syncthreads();
        if (tid < 512) {
            float pv;
            if ((tid >> 6) == g) pv = pown_s[tid & 63];
            else                 pv = __uint_as_float(ld_agent_u(&pBb[tid]));
            p_s[tid] = pv;
            float dv = pv;
            dv += __shfl_xor(dv, 1);  dv += __shfl_xor(dv, 2);  dv += __shfl_xor(dv, 4);
            dv += __shfl_xor(dv, 8);  dv += __shfl_xor(dv, 16); dv += __shfl_xor(dv, 32);
            if ((tid & 63) == 0) red_s[tid >> 6] = dv;
        }
        __syncthreads();
        float inv;
        {
            float tot = red_s[0] + red_s[1] + red_s[2] + red_s[3]
                      + red_s[4] + red_s[5] + red_s[6] + red_s[7];
            inv = 1.0f / tot;
        }

        // ---- phase 4: zc for own col from LDS AW2 (p broadcast-read) ----
        {
            float zc = 0.0f;
#pragma unroll
            for (int i = 0; i < 32; ++i) {
                float2 pv = *(const float2*)&p_s[ks * 64 + 2 * i];
                unsigned w = aw2L[(ks * 32 + i) * 128 + cc];
                zc += pv.x * bf_lo(w) + pv.y * bf_hi(w);
            }
            zp_s[ks][cc] = zc;
        }
        __syncthreads();
        if (tid < 128) {
            float zcs = zp_s[0][cc] + zp_s[1][cc] + zp_s[2][cc] + zp_s[3][cc]
                      + zp_s[4][cc] + zp_s[5][cc] + zp_s[6][cc] + zp_s[7][cc];
            z_s[cc] = zv + zcs * inv;
        }
        __syncthreads();

        // ---- phase 5: gates + state for own 32 units; exchange 2: h ----
        if (tid < 32) {
            float zi = z_s[tid], zf = z_s[32 + tid], zg = z_s[64 + tid], zo = z_s[96 + tid];
            float ig = sigmoidf_fast(zi);
            float fg = sigmoidf_fast(zf);
            float gg = tanhf_fast(zg);
            float og = sigmoidf_fast(zo);
            float cn = fg * c_r + ig * gg;
            float hn = og * tanhf_fast(cn);
            c_r = cn;
            int u = g * 32 + tid;
            h_s[u] = hn;
            st_agent_u(&hBb[u], __float_as_uint(hn));
            seq[((size_t)b * TSTEPS + t) * UNITS + u] = hn;
            if (t == TSTEPS - 1) { hT[b * UNITS + u] = hn; cT[b * UNITS + u] = cn; }
        }
        if (tid < 64) {   // wave 0: drain payload stores, then sentinel
            asm volatile("s_waitcnt vmcnt(0)" ::: "memory");
            if (tid == 0) st_agent_u(&sentb[8 + g], htag);
        }
        if (tid < 8 && tid != g) {
            while (ld_agent_u(&sentb[8 + tid]) < htag)
                __builtin_amdgcn_s_sleep(1);
        }
        __syncthreads();
        if (tid < 256 && (tid >> 5) != g)
            h_s[tid] = __uint_as_float(ld_agent_u(&hBb[tid]));
        __syncthreads();
    }
}

// ---------------------------------------------------------------------------
extern "C" void kernel_launch(void* const* d_in, const int* in_sizes, int n_in,
                              void* d_out, int out_size, void* d_ws, size_t ws_size,
                              hipStream_t stream)
{
    (void)in_sizes; (void)n_in; (void)out_size; (void)ws_size;
    const float* inputs   = (const float*)d_in[0];
    const float* attended = (const float*)d_in[1];
    const float* key_W    = (const float*)d_in[2];
    const float* key_b    = (const float*)d_in[3];
    const float* query_W  = (const float*)d_in[4];
    const float* query_b  = (const float*)d_in[5];
    const float* attn_W   = (const float*)d_in[6];
    const float* lstm_W   = (const float*)d_in[8];
    const float* lstm_U   = (const float*)d_in[9];
    const float* lstm_b   = (const float*)d_in[10];
    // attn_b (d_in[7]) cancels in softmax — dropped.

    float* out = (float*)d_out;
    float* seq = out;
    float* hT  = out + (size_t)BATCH * TSTEPS * UNITS;
    float* cT  = hT + BATCH * UNITS;

    float* ws = (float*)d_ws;
    float* keys = ws;                                        // 2,097,152 f
    float* pre  = keys + 2097152;                            // 2,097,152 f
    unsigned short* aw2T = (unsigned short*)(pre + 2097152); // 16*1024*512 ushort
    unsigned* pB   = (unsigned*)(aw2T + (size_t)16 * 1024 * 512); // 16*512 u32
    unsigned* hB   = pB + BATCH * 512;                            // 16*256 u32
    unsigned* sent = hB + BATCH * 256;                            // 16*16 u32

    // sentinels zeroed each launch (tags are >=1) — replay-safe
    hipMemsetAsync(sent, 0, (size_t)BATCH * 16 * sizeof(unsigned), stream);

    // keys = attended @ key_W + key_b          (8192 x 256)
    gemm_bias_kernel<<<dim3(128, 4), 256, 0, stream>>>(
        attended, key_W, key_b, keys, 8192, 256, 256);
    // pre = inputs @ lstm_W[:256] + lstm_b     (2048 x 1024)
    gemm_bias_kernel<<<dim3(32, 16), 256, 0, stream>>>(
        inputs, lstm_W, lstm_b, pre, 2048, 1024, 256);
    // AW2^T (bf16) = (attended @ lstm_W[256:])^T per batch: [b][1024][512]
    gemm_T_bf16_kernel<<<dim3(128, 16), 256, 0, stream>>>(
        attended, lstm_W + (size_t)256 * ZDIM, aw2T, 8192, 1024, 256);

    rnn_persistent<<<dim3(NBLK), dim3(NTHR), 0, stream>>>(
        query_W, query_b, attn_W, lstm_U,
        keys, pre, aw2T, pB, hB, sent, seq, hT, cT);
}